// Round 7
// baseline (303.951 us; speedup 1.0000x reference)
//
#include <hip/hip_runtime.h>
#include <cmath>

#define B_SZ  1024
#define NORB  128
#define NUP   32
#define HID   4096
#define NCORR (NORB * NUP)   // 4096
#define K1    (4 * NORB)     // 512, one-hot GEMM K-dim

typedef short  bf16x8 __attribute__((ext_vector_type(8)));
typedef float  f32x4  __attribute__((ext_vector_type(4)));

__device__ __forceinline__ unsigned short f2bf_rne(float f) {
    unsigned int u = __float_as_uint(f);
    u += 0x7FFFu + ((u >> 16) & 1u);
    return (unsigned short)(u >> 16);
}

// ---------------------------------------------------------------------------
// k_packx: x [1024][128] int32 (codes 0..3) -> xp [1024][8] dwords, 2b/orbital.
// ---------------------------------------------------------------------------
__global__ __launch_bounds__(256) void k_packx(const int* __restrict__ x,
                                               unsigned int* __restrict__ xp) {
    int t = threadIdx.x;
    int row = blockIdx.x * 32 + (t >> 3);
    int d = t & 7;
    const int* src = x + row * NORB + d * 16;
    unsigned int dw = 0;
#pragma unroll
    for (int b = 0; b < 16; ++b) dw |= ((unsigned int)(src[b] & 3)) << (2 * b);
    xp[row * 8 + d] = dw;
}

// ---------------------------------------------------------------------------
// k_splitW: W [rows][4096] f32 -> hi/lo bf16 in MFMA B-FRAGMENT ORDER:
//   flat = ((nt*ktTot + kt)*64 + lane)*8 + j
//   nt=n>>4, kt=k>>5, lane=((k>>3)&3)*16 + (n&15), j=k&7.
// ---------------------------------------------------------------------------
__global__ __launch_bounds__(256) void k_splitW(const float* __restrict__ W,
                                                unsigned short* __restrict__ Bph,
                                                unsigned short* __restrict__ Bpl,
                                                int ktTot) {
    __shared__ float tile[64][33];
    int n0 = blockIdx.x * 32, k0 = blockIdx.y * 64;
    int t = threadIdx.x;
    int nl = t & 31, kg = t >> 5;
#pragma unroll
    for (int i = 0; i < 8; ++i) {
        int kl = kg + i * 8;
        tile[kl][nl] = W[(size_t)(k0 + kl) * 4096 + n0 + nl];
    }
    __syncthreads();

    int nt = (n0 + nl) >> 4;
    int kt = (k0 >> 5) + (kg >> 2);
    int lane_o = (kg & 3) * 16 + (nl & 15);
    size_t o = (((size_t)nt * ktTot + kt) * 64 + lane_o) * 8;

    unsigned short hi8[8], lo8[8];
#pragma unroll
    for (int j = 0; j < 8; ++j) {
        float v = tile[kg * 8 + j][nl];
        unsigned short hi = f2bf_rne(v);
        float fhi = __uint_as_float((unsigned int)hi << 16);
        hi8[j] = hi;
        lo8[j] = f2bf_rne(v - fhi);
    }
    *(bf16x8*)(Bph + o) = *(bf16x8*)hi8;
    *(bf16x8*)(Bpl + o) = *(bf16x8*)lo8;
}

// ---------------------------------------------------------------------------
// k_hidden2: h = relu(one_hot(x) @ (W1hi + W1lo) + b1).
// Output: A-FRAGMENT-PACKED split-bf16 (layout as k_gemm5 expects).
// ---------------------------------------------------------------------------
__global__ __launch_bounds__(256) void k_hidden2(const unsigned int* __restrict__ xp,
                                                 const unsigned short* __restrict__ Bph,
                                                 const unsigned short* __restrict__ Bpl,
                                                 const float* __restrict__ b1,
                                                 unsigned short* __restrict__ h_hi,
                                                 unsigned short* __restrict__ h_lo) {
    __shared__ unsigned int sxp[64][8];
    __shared__ float Ht[64][132];

    int n0 = blockIdx.x * 128;
    int m0 = blockIdx.y * 64;
    int t = threadIdx.x;
    int w = t >> 6, lane = t & 63;
    int lm = lane & 15, kq = lane >> 4;
    int wn = w * 32;

#pragma unroll
    for (int i = 0; i < 2; ++i) {
        int idx = t + 256 * i;
        sxp[idx >> 3][idx & 7] = xp[(m0 + (idx >> 3)) * 8 + (idx & 7)];
    }
    __syncthreads();

    size_t nt0 = (size_t)((n0 + wn) >> 4);
    const unsigned short* bph = Bph + nt0 * (16 * 512) + (size_t)lane * 8;
    const unsigned short* bpl = Bpl + nt0 * (16 * 512) + (size_t)lane * 8;

    f32x4 acc[4][2] = {};

    bf16x8 nbh0 = *(const bf16x8*)(bph);
    bf16x8 nbh1 = *(const bf16x8*)(bph + 16 * 512);
    bf16x8 nbl0 = *(const bf16x8*)(bpl);
    bf16x8 nbl1 = *(const bf16x8*)(bpl + 16 * 512);

    for (int kt = 0; kt < 16; ++kt) {
        bf16x8 bh0 = nbh0, bh1 = nbh1, bl0 = nbl0, bl1 = nbl1;
        if (kt + 1 < 16) {
            nbh0 = *(const bf16x8*)(bph + (kt + 1) * 512);
            nbh1 = *(const bf16x8*)(bph + 16 * 512 + (kt + 1) * 512);
            nbl0 = *(const bf16x8*)(bpl + (kt + 1) * 512);
            nbl1 = *(const bf16x8*)(bpl + 16 * 512 + (kt + 1) * 512);
        }

        int i0 = kt * 8 + kq * 2;
        int dwIdx = i0 >> 4;
        int sh = (i0 & 15) * 2;
        bf16x8 af[4];
#pragma unroll
        for (int fm = 0; fm < 4; ++fm) {
            unsigned int dw = sxp[fm * 16 + lm][dwIdx];
            unsigned int c01 = (dw >> sh) & 0xFu;
            union { bf16x8 v; unsigned long long u[2]; } a;
            a.u[0] = 0x3F80ULL << ((c01 & 3u) * 16);
            a.u[1] = 0x3F80ULL << ((c01 >> 2) * 16);
            af[fm] = a.v;
        }

#pragma unroll
        for (int fm = 0; fm < 4; ++fm) {
            acc[fm][0] = __builtin_amdgcn_mfma_f32_16x16x32_bf16(af[fm], bh0, acc[fm][0], 0, 0, 0);
            acc[fm][0] = __builtin_amdgcn_mfma_f32_16x16x32_bf16(af[fm], bl0, acc[fm][0], 0, 0, 0);
            acc[fm][1] = __builtin_amdgcn_mfma_f32_16x16x32_bf16(af[fm], bh1, acc[fm][1], 0, 0, 0);
            acc[fm][1] = __builtin_amdgcn_mfma_f32_16x16x32_bf16(af[fm], bl1, acc[fm][1], 0, 0, 0);
        }
    }

    // epilogue: bias+relu into LDS (D-layout), read back in A-frag order
#pragma unroll
    for (int fm = 0; fm < 4; ++fm)
#pragma unroll
        for (int fn = 0; fn < 2; ++fn) {
            int n = wn + fn * 16 + lm;
            float bv = b1[n0 + n];
#pragma unroll
            for (int r = 0; r < 4; ++r)
                Ht[fm * 16 + kq * 4 + r][n] = fmaxf(acc[fm][fn][r] + bv, 0.f);
        }
    __syncthreads();

    size_t mt0 = (size_t)(m0 >> 4), kt0 = (size_t)(n0 >> 5);
#pragma unroll
    for (int fi = 0; fi < 4; ++fi) {
        int f = w * 4 + fi;
        int mt = f >> 2, ktn = f & 3;
        int m = mt * 16 + lm;
        int kn = ktn * 32 + kq * 8;
        float4 v0 = *(const float4*)&Ht[m][kn];
        float4 v1 = *(const float4*)&Ht[m][kn + 4];
        float vv[8] = {v0.x, v0.y, v0.z, v0.w, v1.x, v1.y, v1.z, v1.w};
        unsigned short hi8[8], lo8[8];
#pragma unroll
        for (int j = 0; j < 8; ++j) {
            unsigned short hi = f2bf_rne(vv[j]);
            float fhi = __uint_as_float((unsigned int)hi << 16);
            hi8[j] = hi;
            lo8[j] = f2bf_rne(vv[j] - fhi);
        }
        size_t o = (((mt0 + mt) * 128 + (kt0 + ktn)) * 64 + lane) * 8;
        *(bf16x8*)(h_hi + o) = *(bf16x8*)hi8;
        *(bf16x8*)(h_lo + o) = *(bf16x8*)lo8;
    }
}

// ---------------------------------------------------------------------------
// f32 fallback hidden
// ---------------------------------------------------------------------------
__global__ __launch_bounds__(256) void k_hidden_f32(const int* __restrict__ x,
                                                    const float* __restrict__ W1,
                                                    const float* __restrict__ b1,
                                                    float* __restrict__ h) {
    int b = blockIdx.x, tid = threadIdx.x;
    __shared__ int sx[NORB];
    if (tid < NORB) sx[tid] = x[b * NORB + tid];
    __syncthreads();
    float acc[16];
#pragma unroll
    for (int u = 0; u < 16; ++u) acc[u] = b1[tid + 256 * u];
    for (int i = 0; i < NORB; ++i) {
        const float* row = W1 + (size_t)(4 * i + sx[i]) * HID;
#pragma unroll
        for (int u = 0; u < 16; ++u) acc[u] += row[tid + 256 * u];
    }
    float* hb = h + (size_t)b * HID;
#pragma unroll
    for (int u = 0; u < 16; ++u) hb[tid + 256 * u] = fmaxf(acc[u], 0.f);
}

// ---------------------------------------------------------------------------
// k_gemm5: corr = (h_hi+h_lo)@W2_hi + h_hi@W2_lo + b2. No LDS, no barriers.
// Ping-pong register pipeline (fc/fn), 12 uniform SGPR stream bases + one
// divergent 32-bit offset shared by all loads. __launch_bounds__(256,2)
// lifts the VGPR cap so the 24-fragment pipeline stays in registers
// (round-6 failure: 72 VGPR -> prefetch collapsed, latency exposed).
// ---------------------------------------------------------------------------
__global__ __launch_bounds__(256, 2) void k_gemm5(const unsigned short* __restrict__ Ahp,
                                                  const unsigned short* __restrict__ Alp,
                                                  const unsigned short* __restrict__ Bph,
                                                  const unsigned short* __restrict__ Bpl,
                                                  const float* __restrict__ bias,
                                                  float* __restrict__ C) {
    int n0 = blockIdx.x * 128;
    int m0 = blockIdx.y * 64;
    int t = threadIdx.x;
    int w = t >> 6, lane = t & 63;
    int lm = lane & 15, kq = lane >> 4;
    int wn = w * 32;

    int mt0 = m0 >> 4;
    int nt0 = (n0 + wn) >> 4;

    // 12 wave-uniform stream bases (SGPR); frag (stream, kt) = base + kt*512
    const unsigned short* __restrict__ s_ah[4];
    const unsigned short* __restrict__ s_al[4];
    const unsigned short* __restrict__ s_bh[2];
    const unsigned short* __restrict__ s_bl[2];
#pragma unroll
    for (int i = 0; i < 4; ++i) {
        s_ah[i] = Ahp + (size_t)(mt0 + i) * 65536;
        s_al[i] = Alp + (size_t)(mt0 + i) * 65536;
    }
#pragma unroll
    for (int i = 0; i < 2; ++i) {
        s_bh[i] = Bph + (size_t)(nt0 + i) * 65536;
        s_bl[i] = Bpl + (size_t)(nt0 + i) * 65536;
    }
    int off0 = lane * 8;   // divergent element offset, shared by all streams

    f32x4 acc[4][2] = {};
    bf16x8 fc[12], fn[12];

#define LOADSET(dst, koff) do {                                         \
        int _o = off0 + (koff) * 512;                                   \
        dst[0]  = *(const bf16x8*)(s_ah[0] + _o);                       \
        dst[1]  = *(const bf16x8*)(s_ah[1] + _o);                       \
        dst[2]  = *(const bf16x8*)(s_ah[2] + _o);                       \
        dst[3]  = *(const bf16x8*)(s_ah[3] + _o);                       \
        dst[4]  = *(const bf16x8*)(s_al[0] + _o);                       \
        dst[5]  = *(const bf16x8*)(s_al[1] + _o);                       \
        dst[6]  = *(const bf16x8*)(s_al[2] + _o);                       \
        dst[7]  = *(const bf16x8*)(s_al[3] + _o);                       \
        dst[8]  = *(const bf16x8*)(s_bh[0] + _o);                       \
        dst[9]  = *(const bf16x8*)(s_bh[1] + _o);                       \
        dst[10] = *(const bf16x8*)(s_bl[0] + _o);                       \
        dst[11] = *(const bf16x8*)(s_bl[1] + _o);                       \
    } while (0)

#define MFMASET(f) do {                                                 \
        _Pragma("unroll")                                               \
        for (int fm = 0; fm < 4; ++fm) {                                \
            acc[fm][0] = __builtin_amdgcn_mfma_f32_16x16x32_bf16(f[fm],     f[8],  acc[fm][0], 0, 0, 0); \
            acc[fm][0] = __builtin_amdgcn_mfma_f32_16x16x32_bf16(f[4 + fm], f[8],  acc[fm][0], 0, 0, 0); \
            acc[fm][0] = __builtin_amdgcn_mfma_f32_16x16x32_bf16(f[fm],     f[10], acc[fm][0], 0, 0, 0); \
            acc[fm][1] = __builtin_amdgcn_mfma_f32_16x16x32_bf16(f[fm],     f[9],  acc[fm][1], 0, 0, 0); \
            acc[fm][1] = __builtin_amdgcn_mfma_f32_16x16x32_bf16(f[4 + fm], f[9],  acc[fm][1], 0, 0, 0); \
            acc[fm][1] = __builtin_amdgcn_mfma_f32_16x16x32_bf16(f[fm],     f[11], acc[fm][1], 0, 0, 0); \
        }                                                               \
    } while (0)

    LOADSET(fc, 0);
    for (int kt = 0; kt < 128; kt += 2) {
        LOADSET(fn, kt + 1);
        MFMASET(fc);
        int k2 = (kt + 2 < 128) ? kt + 2 : 127;   // clamp: stays in-bounds
        LOADSET(fc, k2);
        MFMASET(fn);
    }
#undef LOADSET
#undef MFMASET

    // epilogue: bias + store
#pragma unroll
    for (int fm = 0; fm < 4; ++fm)
#pragma unroll
        for (int fnn = 0; fnn < 2; ++fnn) {
            int n = n0 + wn + fnn * 16 + lm;
            float bv = bias[n];
#pragma unroll
            for (int r = 0; r < 4; ++r) {
                int m = m0 + fm * 16 + kq * 4 + r;
                C[(size_t)m * NCORR + n] = acc[fm][fnn][r] + bv;
            }
        }
}

// ---------------------------------------------------------------------------
// f32 fallback GEMM (round-2 kernel, unchanged)
// ---------------------------------------------------------------------------
#define BM 64
#define BN 64
#define BK 32
__global__ __launch_bounds__(256) void k_gemm(const float* __restrict__ A,
                                              const float* __restrict__ Bm,
                                              const float* __restrict__ bias,
                                              float* __restrict__ C) {
    __shared__ float As[BK][68];
    __shared__ float Bs[BK][BN];
    int n0 = blockIdx.x * BN, m0 = blockIdx.y * BM;
    int tid = threadIdx.x;
    int tm = tid >> 4, tn = tid & 15;
    int am = tid >> 3, ak = (tid & 7) * 4;
    int bk = tid >> 4, bn = (tid & 15) * 4;
    float acc[4][4] = {};
    for (int k0 = 0; k0 < HID; k0 += BK) {
#pragma unroll
        for (int s = 0; s < 2; ++s) {
            int m = am + 32 * s;
            float4 v = *(const float4*)(A + (size_t)(m0 + m) * HID + k0 + ak);
            As[ak + 0][m] = v.x; As[ak + 1][m] = v.y;
            As[ak + 2][m] = v.z; As[ak + 3][m] = v.w;
        }
#pragma unroll
        for (int s = 0; s < 2; ++s) {
            int k = bk + 16 * s;
            float4 v = *(const float4*)(Bm + (size_t)(k0 + k) * NCORR + n0 + bn);
            *(float4*)&Bs[k][bn] = v;
        }
        __syncthreads();
#pragma unroll
        for (int kk = 0; kk < BK; ++kk) {
            float4 a = *(const float4*)&As[kk][tm * 4];
            float4 bv = *(const float4*)&Bs[kk][tn * 4];
            float av[4] = {a.x, a.y, a.z, a.w};
            float bb[4] = {bv.x, bv.y, bv.z, bv.w};
#pragma unroll
            for (int i = 0; i < 4; ++i)
#pragma unroll
                for (int j = 0; j < 4; ++j) acc[i][j] += av[i] * bb[j];
        }
        __syncthreads();
    }
#pragma unroll
    for (int i = 0; i < 4; ++i) {
        int m = m0 + tm * 4 + i;
        float4 o;
        o.x = acc[i][0] + bias[n0 + tn * 4 + 0];
        o.y = acc[i][1] + bias[n0 + tn * 4 + 1];
        o.z = acc[i][2] + bias[n0 + tn * 4 + 2];
        o.w = acc[i][3] + bias[n0 + tn * 4 + 3];
        *(float4*)(C + (size_t)m * NCORR + n0 + tn * 4) = o;
    }
}

// ---------------------------------------------------------------------------
// Kernel C: gather + 32x32 LU (partial pivoting) per spin, planar complex out.
// ---------------------------------------------------------------------------
__global__ __launch_bounds__(128) void k_det(const int* __restrict__ x,
                                             const float* __restrict__ orbitals,
                                             const float* __restrict__ corr,
                                             float* __restrict__ out,
                                             int imag_off) {
    int b = blockIdx.x, tid = threadIdx.x;
    __shared__ int sx[NORB];
    __shared__ int yup[NUP], ydn[NUP];
    __shared__ float M[2][NUP][NUP + 1];
    __shared__ float rlog[2];
    __shared__ int rneg[2];

    sx[tid] = x[b * NORB + tid];
    __syncthreads();

    int occ = sx[tid];
    if (occ & 1) {
        int r = 0;
        for (int i = 0; i < tid; ++i) r += sx[i] & 1;
        yup[r] = tid;
    }
    if (occ & 2) {
        int r = 0;
        for (int i = 0; i < tid; ++i) r += (sx[i] >> 1) & 1;
        ydn[r] = tid;
    }
    __syncthreads();

    const float* cb = corr + (size_t)b * NCORR;
    for (int idx = tid; idx < 2 * NUP * NUP; idx += 128) {
        int s = idx >> 10;
        int i = (idx >> 5) & 31;
        int j = idx & 31;
        int r = s ? ydn[i] : yup[i];
        M[s][i][j] = orbitals[r * NUP + j] + cb[r * NUP + j];
    }
    __syncthreads();

    int wv = tid >> 6, lane = tid & 63;
    float (*Mm)[NUP + 1] = M[wv];
    float logdet = 0.f;
    int neg = 0;

    for (int k = 0; k < NUP; ++k) {
        float v = (lane >= k && lane < NUP) ? fabsf(Mm[lane][k]) : -1.f;
        int pi = lane;
#pragma unroll
        for (int off = 32; off > 0; off >>= 1) {
            float v2 = __shfl_down(v, off);
            int p2 = __shfl_down(pi, off);
            if (v2 > v) { v = v2; pi = p2; }
        }
        int p = __shfl(pi, 0);

        if (p != k) {
            if (lane < NUP) {
                float t1 = Mm[k][lane];
                Mm[k][lane] = Mm[p][lane];
                Mm[p][lane] = t1;
            }
            neg ^= 1;
        }
        __syncthreads();

        float pv = Mm[k][k];
        logdet += logf(fabsf(pv));
        if (pv < 0.f) neg ^= 1;

        int row = k + 1 + (lane & 31);
        int half = lane >> 5;
        if (row < NUP) {
            float f = Mm[row][k] / pv;
            for (int j = k + 1 + half; j < NUP; j += 2)
                Mm[row][j] -= f * Mm[k][j];
        }
        __syncthreads();
    }

    if (lane == 0) { rlog[wv] = logdet; rneg[wv] = neg; }
    __syncthreads();
    if (tid == 0) {
        out[b] = rlog[0] + rlog[1];
        if (imag_off > 0)
            out[imag_off + b] =
                (rneg[0] ^ rneg[1]) ? 3.14159265358979323846f : 0.f;
    }
}

// ---------------------------------------------------------------------------
extern "C" void kernel_launch(void* const* d_in, const int* in_sizes, int n_in,
                              void* d_out, int out_size, void* d_ws, size_t ws_size,
                              hipStream_t stream) {
    const int*   x        = (const int*)d_in[0];
    const float* orbitals = (const float*)d_in[1];
    const float* W1       = (const float*)d_in[2];
    const float* b1       = (const float*)d_in[3];
    const float* W2       = (const float*)d_in[4];
    const float* b2       = (const float*)d_in[5];
    float* out = (float*)d_out;
    int imag_off = (out_size == 2 * B_SZ) ? B_SZ : 0;

    const size_t need = (size_t)96 * 1024 * 1024;
    if (ws_size >= need) {
        unsigned short* h_hi = (unsigned short*)d_ws;                    //  8 MB (A-frag packed)
        unsigned short* h_lo = h_hi + (size_t)B_SZ * HID;                //  8 MB
        unsigned short* Bph  = h_lo + (size_t)B_SZ * HID;                // 32 MB (B-frag packed)
        unsigned short* Bpl  = Bph + (size_t)HID * NCORR;                // 32 MB
        float*          corr = (float*)(Bpl + (size_t)HID * NCORR);     // 16 MB

        unsigned short* W1ph = (unsigned short*)corr;                    // 4 MB (inside corr)
        unsigned short* W1pl = W1ph + (size_t)K1 * HID;                  // 4 MB
        unsigned int*   xp   = (unsigned int*)(W1pl + (size_t)K1 * HID); // 32 KB

        k_packx<<<B_SZ / 32, 256, 0, stream>>>(x, xp);
        k_splitW<<<dim3(HID / 32, K1 / 64), 256, 0, stream>>>(W1, W1ph, W1pl, 16);
        k_splitW<<<dim3(NCORR / 32, HID / 64), 256, 0, stream>>>(W2, Bph, Bpl, 128);

        k_hidden2<<<dim3(HID / 128, B_SZ / 64), 256, 0, stream>>>(xp, W1ph, W1pl, b1, h_hi, h_lo);

        dim3 g2(NCORR / 128, B_SZ / 64);    // 32 x 16 = 512 blocks
        k_gemm5<<<g2, 256, 0, stream>>>(h_hi, h_lo, Bph, Bpl, b2, corr);
        k_det<<<B_SZ, 128, 0, stream>>>(x, orbitals, corr, out, imag_off);
    } else {
        float* h    = (float*)d_ws;
        float* corr = h + (size_t)B_SZ * HID;
        k_hidden_f32<<<B_SZ, 256, 0, stream>>>(x, W1, b1, h);
        dim3 g2(NCORR / BN, B_SZ / BM);
        k_gemm<<<g2, 256, 0, stream>>>(h, W2, b2, corr);
        k_det<<<B_SZ, 128, 0, stream>>>(x, orbitals, corr, out, imag_off);
    }
}

// Round 8
// 261.317 us; speedup vs baseline: 1.1631x; 1.1631x over previous
//
#include <hip/hip_runtime.h>
#include <cmath>

#define B_SZ  1024
#define NORB  128
#define NUP   32
#define HID   4096
#define NCORR (NORB * NUP)   // 4096
#define K1    (4 * NORB)     // 512, one-hot GEMM K-dim

typedef short  bf16x8 __attribute__((ext_vector_type(8)));
typedef float  f32x4  __attribute__((ext_vector_type(4)));

__device__ __forceinline__ unsigned short f2bf_rne(float f) {
    unsigned int u = __float_as_uint(f);
    u += 0x7FFFu + ((u >> 16) & 1u);
    return (unsigned short)(u >> 16);
}

// ---------------------------------------------------------------------------
// k_splitW: W [rows][4096] f32 -> hi/lo bf16 in MFMA B-FRAGMENT ORDER:
//   flat = ((nt*ktTot + kt)*64 + lane)*8 + j
//   nt=n>>4, kt=k>>5, lane=((k>>3)&3)*16 + (n&15), j=k&7.
// float4 global reads (4x fewer load insts than scalar). Tile 64k x 32n.
// ---------------------------------------------------------------------------
__global__ __launch_bounds__(256) void k_splitW(const float* __restrict__ W,
                                                unsigned short* __restrict__ Bph,
                                                unsigned short* __restrict__ Bpl,
                                                int ktTot) {
    __shared__ float tile[64][33];
    int n0 = blockIdx.x * 32, k0 = blockIdx.y * 64;
    int t = threadIdx.x;

    // load: 64 rows x 32 floats; thread t covers row (t>>3)+{0,32}, col (t&7)*4
    int rl = t >> 3, c4 = (t & 7) * 4;
#pragma unroll
    for (int i = 0; i < 2; ++i) {
        int kl = rl + 32 * i;
        float4 v = *(const float4*)(W + (size_t)(k0 + kl) * 4096 + n0 + c4);
        tile[kl][c4 + 0] = v.x; tile[kl][c4 + 1] = v.y;
        tile[kl][c4 + 2] = v.z; tile[kl][c4 + 3] = v.w;
    }
    __syncthreads();

    int nl = t & 31, kg = t >> 5;          // nl: 0..31, kg: 0..7
    int nt = (n0 + nl) >> 4;
    int kt = (k0 >> 5) + (kg >> 2);
    int lane_o = (kg & 3) * 16 + (nl & 15);
    size_t o = (((size_t)nt * ktTot + kt) * 64 + lane_o) * 8;

    unsigned short hi8[8], lo8[8];
#pragma unroll
    for (int j = 0; j < 8; ++j) {
        float v = tile[kg * 8 + j][nl];
        unsigned short hi = f2bf_rne(v);
        float fhi = __uint_as_float((unsigned int)hi << 16);
        hi8[j] = hi;
        lo8[j] = f2bf_rne(v - fhi);
    }
    *(bf16x8*)(Bph + o) = *(bf16x8*)hi8;
    *(bf16x8*)(Bpl + o) = *(bf16x8*)lo8;
}

// ---------------------------------------------------------------------------
// k_hidden2: h = relu(one_hot(x) @ (W1hi + W1lo) + b1).
// x packing folded in (reads x directly; k_packx launch removed).
// Output: A-FRAGMENT-PACKED split-bf16:
//   flat = ((mt*128 + kt)*64 + lane)*8 + j, kt over HID/32.
// ---------------------------------------------------------------------------
__global__ __launch_bounds__(256) void k_hidden2(const int* __restrict__ x,
                                                 const unsigned short* __restrict__ Bph,
                                                 const unsigned short* __restrict__ Bpl,
                                                 const float* __restrict__ b1,
                                                 unsigned short* __restrict__ h_hi,
                                                 unsigned short* __restrict__ h_lo) {
    __shared__ unsigned int sxp[64][8];
    __shared__ float Ht[64][132];

    int n0 = blockIdx.x * 128;
    int m0 = blockIdx.y * 64;
    int t = threadIdx.x;
    int w = t >> 6, lane = t & 63;
    int lm = lane & 15, kq = lane >> 4;
    int wn = w * 32;

    // pack x for this m-tile: 64 rows x 8 dwords (2 bits/orbital)
#pragma unroll
    for (int i = 0; i < 2; ++i) {
        int id = t + 256 * i;            // 0..511
        int row = id >> 3, d = id & 7;
        const int* src = x + (size_t)(m0 + row) * NORB + d * 16;
        unsigned int dw = 0;
#pragma unroll
        for (int b = 0; b < 16; ++b) dw |= ((unsigned int)(src[b] & 3)) << (2 * b);
        sxp[row][d] = dw;
    }
    __syncthreads();

    size_t nt0 = (size_t)((n0 + wn) >> 4);
    const unsigned short* bph = Bph + nt0 * (16 * 512) + (size_t)lane * 8;
    const unsigned short* bpl = Bpl + nt0 * (16 * 512) + (size_t)lane * 8;

    f32x4 acc[4][2] = {};

    bf16x8 nbh0 = *(const bf16x8*)(bph);
    bf16x8 nbh1 = *(const bf16x8*)(bph + 16 * 512);
    bf16x8 nbl0 = *(const bf16x8*)(bpl);
    bf16x8 nbl1 = *(const bf16x8*)(bpl + 16 * 512);

    for (int kt = 0; kt < 16; ++kt) {
        bf16x8 bh0 = nbh0, bh1 = nbh1, bl0 = nbl0, bl1 = nbl1;
        if (kt + 1 < 16) {
            nbh0 = *(const bf16x8*)(bph + (kt + 1) * 512);
            nbh1 = *(const bf16x8*)(bph + 16 * 512 + (kt + 1) * 512);
            nbl0 = *(const bf16x8*)(bpl + (kt + 1) * 512);
            nbl1 = *(const bf16x8*)(bpl + 16 * 512 + (kt + 1) * 512);
        }

        int i0 = kt * 8 + kq * 2;
        int dwIdx = i0 >> 4;
        int sh = (i0 & 15) * 2;
        bf16x8 af[4];
#pragma unroll
        for (int fm = 0; fm < 4; ++fm) {
            unsigned int dw = sxp[fm * 16 + lm][dwIdx];
            unsigned int c01 = (dw >> sh) & 0xFu;
            union { bf16x8 v; unsigned long long u[2]; } a;
            a.u[0] = 0x3F80ULL << ((c01 & 3u) * 16);
            a.u[1] = 0x3F80ULL << ((c01 >> 2) * 16);
            af[fm] = a.v;
        }

#pragma unroll
        for (int fm = 0; fm < 4; ++fm) {
            acc[fm][0] = __builtin_amdgcn_mfma_f32_16x16x32_bf16(af[fm], bh0, acc[fm][0], 0, 0, 0);
            acc[fm][0] = __builtin_amdgcn_mfma_f32_16x16x32_bf16(af[fm], bl0, acc[fm][0], 0, 0, 0);
            acc[fm][1] = __builtin_amdgcn_mfma_f32_16x16x32_bf16(af[fm], bh1, acc[fm][1], 0, 0, 0);
            acc[fm][1] = __builtin_amdgcn_mfma_f32_16x16x32_bf16(af[fm], bl1, acc[fm][1], 0, 0, 0);
        }
    }

    // epilogue: bias+relu into LDS (D-layout), read back in A-frag order
#pragma unroll
    for (int fm = 0; fm < 4; ++fm)
#pragma unroll
        for (int fn = 0; fn < 2; ++fn) {
            int n = wn + fn * 16 + lm;
            float bv = b1[n0 + n];
#pragma unroll
            for (int r = 0; r < 4; ++r)
                Ht[fm * 16 + kq * 4 + r][n] = fmaxf(acc[fm][fn][r] + bv, 0.f);
        }
    __syncthreads();

    size_t mt0 = (size_t)(m0 >> 4), kt0 = (size_t)(n0 >> 5);
#pragma unroll
    for (int fi = 0; fi < 4; ++fi) {
        int f = w * 4 + fi;
        int mt = f >> 2, ktn = f & 3;
        int m = mt * 16 + lm;
        int kn = ktn * 32 + kq * 8;
        float4 v0 = *(const float4*)&Ht[m][kn];
        float4 v1 = *(const float4*)&Ht[m][kn + 4];
        float vv[8] = {v0.x, v0.y, v0.z, v0.w, v1.x, v1.y, v1.z, v1.w};
        unsigned short hi8[8], lo8[8];
#pragma unroll
        for (int j = 0; j < 8; ++j) {
            unsigned short hi = f2bf_rne(vv[j]);
            float fhi = __uint_as_float((unsigned int)hi << 16);
            hi8[j] = hi;
            lo8[j] = f2bf_rne(vv[j] - fhi);
        }
        size_t o = (((mt0 + mt) * 128 + (kt0 + ktn)) * 64 + lane) * 8;
        *(bf16x8*)(h_hi + o) = *(bf16x8*)hi8;
        *(bf16x8*)(h_lo + o) = *(bf16x8*)lo8;
    }
}

// ---------------------------------------------------------------------------
// f32 fallback hidden
// ---------------------------------------------------------------------------
__global__ __launch_bounds__(256) void k_hidden_f32(const int* __restrict__ x,
                                                    const float* __restrict__ W1,
                                                    const float* __restrict__ b1,
                                                    float* __restrict__ h) {
    int b = blockIdx.x, tid = threadIdx.x;
    __shared__ int sx[NORB];
    if (tid < NORB) sx[tid] = x[b * NORB + tid];
    __syncthreads();
    float acc[16];
#pragma unroll
    for (int u = 0; u < 16; ++u) acc[u] = b1[tid + 256 * u];
    for (int i = 0; i < NORB; ++i) {
        const float* row = W1 + (size_t)(4 * i + sx[i]) * HID;
#pragma unroll
        for (int u = 0; u < 16; ++u) acc[u] += row[tid + 256 * u];
    }
    float* hb = h + (size_t)b * HID;
#pragma unroll
    for (int u = 0; u < 16; ++u) hb[tid + 256 * u] = fmaxf(acc[u], 0.f);
}

// ---------------------------------------------------------------------------
// k_gemm6: corr = (h_hi+h_lo)@W2_hi + h_hi@W2_lo + b2, bf16 MFMA, f32 acc.
// k_gemm3 skeleton (the pinned load->LDS-write pattern the compiler
// respects) with BK=64: one barrier pair per 48 MFMAs/wave (2x amortized
// vmcnt-drain vs k_gemm3). A frag-packed global -> regs -> LDS (dedups
// the 4x per-wave A reuse); B frag-packed global -> VGPR.
// ---------------------------------------------------------------------------
__global__ __launch_bounds__(256, 2) void k_gemm6(const unsigned short* __restrict__ Ahp,
                                                  const unsigned short* __restrict__ Alp,
                                                  const unsigned short* __restrict__ Bph,
                                                  const unsigned short* __restrict__ Bpl,
                                                  const float* __restrict__ bias,
                                                  float* __restrict__ C) {
    // [sub-kt][hi/lo][mt][lane*8+j] : 2*2*4*512*2B = 16 KB
    __shared__ unsigned short AF[2][2][4][512];

    int n0 = blockIdx.x * 128;
    int m0 = blockIdx.y * 64;
    int t = threadIdx.x;
    int w = t >> 6, lane = t & 63;
    int lm = lane & 15, kq = lane >> 4;
    int wn = w * 32;

    int mt0 = m0 >> 4;
    int nt0 = (n0 + wn) >> 4;

    // A staging streams: wave w stages mt=w (hi and lo), 16B per lane
    const unsigned short* agh = Ahp + (size_t)(mt0 + w) * 65536 + (size_t)lane * 8;
    const unsigned short* agl = Alp + (size_t)(mt0 + w) * 65536 + (size_t)lane * 8;
    // B streams (this wave's two n-fragments)
    const unsigned short* bh0 = Bph + (size_t)nt0 * 65536 + (size_t)lane * 8;
    const unsigned short* bh1 = Bph + (size_t)(nt0 + 1) * 65536 + (size_t)lane * 8;
    const unsigned short* bl0 = Bpl + (size_t)nt0 * 65536 + (size_t)lane * 8;
    const unsigned short* bl1 = Bpl + (size_t)(nt0 + 1) * 65536 + (size_t)lane * 8;

    f32x4 acc[4][2] = {};

    // prologue: A registers for pair 0 (kt = 0, 1)
    float4 rh0 = *(const float4*)(agh);
    float4 rh1 = *(const float4*)(agh + 512);
    float4 rl0 = *(const float4*)(agl);
    float4 rl1 = *(const float4*)(agl + 512);

    for (int ktp = 0; ktp < 64; ++ktp) {
        if (ktp) __syncthreads();          // prior pair's LDS reads complete

        // B fragments for this pair (drained at barrier-2, ~20 instr away)
        int o0 = (2 * ktp) * 512, o1 = o0 + 512;
        bf16x8 B00h = *(const bf16x8*)(bh0 + o0);
        bf16x8 B01h = *(const bf16x8*)(bh1 + o0);
        bf16x8 B00l = *(const bf16x8*)(bl0 + o0);
        bf16x8 B01l = *(const bf16x8*)(bl1 + o0);
        bf16x8 B10h = *(const bf16x8*)(bh0 + o1);
        bf16x8 B11h = *(const bf16x8*)(bh1 + o1);
        bf16x8 B10l = *(const bf16x8*)(bl0 + o1);
        bf16x8 B11l = *(const bf16x8*)(bl1 + o1);

        // stage A (registers loaded one pair ago; death point pinned here)
        *(float4*)&AF[0][0][w][lane * 8] = rh0;
        *(float4*)&AF[1][0][w][lane * 8] = rh1;
        *(float4*)&AF[0][1][w][lane * 8] = rl0;
        *(float4*)&AF[1][1][w][lane * 8] = rl1;
        __syncthreads();

        // prefetch next pair's A (full pair of MFMAs of slack before use)
        int kn = (ktp + 1 < 64) ? ktp + 1 : 63;
        rh0 = *(const float4*)(agh + (size_t)(2 * kn) * 512);
        rh1 = *(const float4*)(agh + (size_t)(2 * kn + 1) * 512);
        rl0 = *(const float4*)(agl + (size_t)(2 * kn) * 512);
        rl1 = *(const float4*)(agl + (size_t)(2 * kn + 1) * 512);

        // ---- sub-kt 0 ----
        bf16x8 ah[4], al[4];
#pragma unroll
        for (int fm = 0; fm < 4; ++fm) {
            ah[fm] = *(const bf16x8*)&AF[0][0][fm][lane * 8];
            al[fm] = *(const bf16x8*)&AF[0][1][fm][lane * 8];
        }
#pragma unroll
        for (int fm = 0; fm < 4; ++fm) {
            acc[fm][0] = __builtin_amdgcn_mfma_f32_16x16x32_bf16(ah[fm], B00h, acc[fm][0], 0, 0, 0);
            acc[fm][0] = __builtin_amdgcn_mfma_f32_16x16x32_bf16(al[fm], B00h, acc[fm][0], 0, 0, 0);
            acc[fm][0] = __builtin_amdgcn_mfma_f32_16x16x32_bf16(ah[fm], B00l, acc[fm][0], 0, 0, 0);
            acc[fm][1] = __builtin_amdgcn_mfma_f32_16x16x32_bf16(ah[fm], B01h, acc[fm][1], 0, 0, 0);
            acc[fm][1] = __builtin_amdgcn_mfma_f32_16x16x32_bf16(al[fm], B01h, acc[fm][1], 0, 0, 0);
            acc[fm][1] = __builtin_amdgcn_mfma_f32_16x16x32_bf16(ah[fm], B01l, acc[fm][1], 0, 0, 0);
        }

        // ---- sub-kt 1 ----
#pragma unroll
        for (int fm = 0; fm < 4; ++fm) {
            ah[fm] = *(const bf16x8*)&AF[1][0][fm][lane * 8];
            al[fm] = *(const bf16x8*)&AF[1][1][fm][lane * 8];
        }
#pragma unroll
        for (int fm = 0; fm < 4; ++fm) {
            acc[fm][0] = __builtin_amdgcn_mfma_f32_16x16x32_bf16(ah[fm], B10h, acc[fm][0], 0, 0, 0);
            acc[fm][0] = __builtin_amdgcn_mfma_f32_16x16x32_bf16(al[fm], B10h, acc[fm][0], 0, 0, 0);
            acc[fm][0] = __builtin_amdgcn_mfma_f32_16x16x32_bf16(ah[fm], B10l, acc[fm][0], 0, 0, 0);
            acc[fm][1] = __builtin_amdgcn_mfma_f32_16x16x32_bf16(ah[fm], B11h, acc[fm][1], 0, 0, 0);
            acc[fm][1] = __builtin_amdgcn_mfma_f32_16x16x32_bf16(al[fm], B11h, acc[fm][1], 0, 0, 0);
            acc[fm][1] = __builtin_amdgcn_mfma_f32_16x16x32_bf16(ah[fm], B11l, acc[fm][1], 0, 0, 0);
        }
    }

    // epilogue: bias + store
#pragma unroll
    for (int fm = 0; fm < 4; ++fm)
#pragma unroll
        for (int fn = 0; fn < 2; ++fn) {
            int n = n0 + wn + fn * 16 + lm;
            float bv = bias[n];
#pragma unroll
            for (int r = 0; r < 4; ++r) {
                int m = m0 + fm * 16 + kq * 4 + r;
                C[(size_t)m * NCORR + n] = acc[fm][fn][r] + bv;
            }
        }
}

// ---------------------------------------------------------------------------
// f32 fallback GEMM (round-2 kernel, unchanged)
// ---------------------------------------------------------------------------
#define BM 64
#define BN 64
#define BK 32
__global__ __launch_bounds__(256) void k_gemm(const float* __restrict__ A,
                                              const float* __restrict__ Bm,
                                              const float* __restrict__ bias,
                                              float* __restrict__ C) {
    __shared__ float As[BK][68];
    __shared__ float Bs[BK][BN];
    int n0 = blockIdx.x * BN, m0 = blockIdx.y * BM;
    int tid = threadIdx.x;
    int tm = tid >> 4, tn = tid & 15;
    int am = tid >> 3, ak = (tid & 7) * 4;
    int bk = tid >> 4, bn = (tid & 15) * 4;
    float acc[4][4] = {};
    for (int k0 = 0; k0 < HID; k0 += BK) {
#pragma unroll
        for (int s = 0; s < 2; ++s) {
            int m = am + 32 * s;
            float4 v = *(const float4*)(A + (size_t)(m0 + m) * HID + k0 + ak);
            As[ak + 0][m] = v.x; As[ak + 1][m] = v.y;
            As[ak + 2][m] = v.z; As[ak + 3][m] = v.w;
        }
#pragma unroll
        for (int s = 0; s < 2; ++s) {
            int k = bk + 16 * s;
            float4 v = *(const float4*)(Bm + (size_t)(k0 + k) * NCORR + n0 + bn);
            *(float4*)&Bs[k][bn] = v;
        }
        __syncthreads();
#pragma unroll
        for (int kk = 0; kk < BK; ++kk) {
            float4 a = *(const float4*)&As[kk][tm * 4];
            float4 bv = *(const float4*)&Bs[kk][tn * 4];
            float av[4] = {a.x, a.y, a.z, a.w};
            float bb[4] = {bv.x, bv.y, bv.z, bv.w};
#pragma unroll
            for (int i = 0; i < 4; ++i)
#pragma unroll
                for (int j = 0; j < 4; ++j) acc[i][j] += av[i] * bb[j];
        }
        __syncthreads();
    }
#pragma unroll
    for (int i = 0; i < 4; ++i) {
        int m = m0 + tm * 4 + i;
        float4 o;
        o.x = acc[i][0] + bias[n0 + tn * 4 + 0];
        o.y = acc[i][1] + bias[n0 + tn * 4 + 1];
        o.z = acc[i][2] + bias[n0 + tn * 4 + 2];
        o.w = acc[i][3] + bias[n0 + tn * 4 + 3];
        *(float4*)(C + (size_t)m * NCORR + n0 + tn * 4) = o;
    }
}

// ---------------------------------------------------------------------------
// Kernel C: gather + 32x32 LU (partial pivoting) per spin, planar complex out.
// ---------------------------------------------------------------------------
__global__ __launch_bounds__(128) void k_det(const int* __restrict__ x,
                                             const float* __restrict__ orbitals,
                                             const float* __restrict__ corr,
                                             float* __restrict__ out,
                                             int imag_off) {
    int b = blockIdx.x, tid = threadIdx.x;
    __shared__ int sx[NORB];
    __shared__ int yup[NUP], ydn[NUP];
    __shared__ float M[2][NUP][NUP + 1];
    __shared__ float rlog[2];
    __shared__ int rneg[2];

    sx[tid] = x[b * NORB + tid];
    __syncthreads();

    int occ = sx[tid];
    if (occ & 1) {
        int r = 0;
        for (int i = 0; i < tid; ++i) r += sx[i] & 1;
        yup[r] = tid;
    }
    if (occ & 2) {
        int r = 0;
        for (int i = 0; i < tid; ++i) r += (sx[i] >> 1) & 1;
        ydn[r] = tid;
    }
    __syncthreads();

    const float* cb = corr + (size_t)b * NCORR;
    for (int idx = tid; idx < 2 * NUP * NUP; idx += 128) {
        int s = idx >> 10;
        int i = (idx >> 5) & 31;
        int j = idx & 31;
        int r = s ? ydn[i] : yup[i];
        M[s][i][j] = orbitals[r * NUP + j] + cb[r * NUP + j];
    }
    __syncthreads();

    int wv = tid >> 6, lane = tid & 63;
    float (*Mm)[NUP + 1] = M[wv];
    float logdet = 0.f;
    int neg = 0;

    for (int k = 0; k < NUP; ++k) {
        float v = (lane >= k && lane < NUP) ? fabsf(Mm[lane][k]) : -1.f;
        int pi = lane;
#pragma unroll
        for (int off = 32; off > 0; off >>= 1) {
            float v2 = __shfl_down(v, off);
            int p2 = __shfl_down(pi, off);
            if (v2 > v) { v = v2; pi = p2; }
        }
        int p = __shfl(pi, 0);

        if (p != k) {
            if (lane < NUP) {
                float t1 = Mm[k][lane];
                Mm[k][lane] = Mm[p][lane];
                Mm[p][lane] = t1;
            }
            neg ^= 1;
        }
        __syncthreads();

        float pv = Mm[k][k];
        logdet += logf(fabsf(pv));
        if (pv < 0.f) neg ^= 1;

        int row = k + 1 + (lane & 31);
        int half = lane >> 5;
        if (row < NUP) {
            float f = Mm[row][k] / pv;
            for (int j = k + 1 + half; j < NUP; j += 2)
                Mm[row][j] -= f * Mm[k][j];
        }
        __syncthreads();
    }

    if (lane == 0) { rlog[wv] = logdet; rneg[wv] = neg; }
    __syncthreads();
    if (tid == 0) {
        out[b] = rlog[0] + rlog[1];
        if (imag_off > 0)
            out[imag_off + b] =
                (rneg[0] ^ rneg[1]) ? 3.14159265358979323846f : 0.f;
    }
}

// ---------------------------------------------------------------------------
extern "C" void kernel_launch(void* const* d_in, const int* in_sizes, int n_in,
                              void* d_out, int out_size, void* d_ws, size_t ws_size,
                              hipStream_t stream) {
    const int*   x        = (const int*)d_in[0];
    const float* orbitals = (const float*)d_in[1];
    const float* W1       = (const float*)d_in[2];
    const float* b1       = (const float*)d_in[3];
    const float* W2       = (const float*)d_in[4];
    const float* b2       = (const float*)d_in[5];
    float* out = (float*)d_out;
    int imag_off = (out_size == 2 * B_SZ) ? B_SZ : 0;

    const size_t need = (size_t)96 * 1024 * 1024;
    if (ws_size >= need) {
        unsigned short* h_hi = (unsigned short*)d_ws;                    //  8 MB (A-frag packed)
        unsigned short* h_lo = h_hi + (size_t)B_SZ * HID;                //  8 MB
        unsigned short* Bph  = h_lo + (size_t)B_SZ * HID;                // 32 MB (B-frag packed)
        unsigned short* Bpl  = Bph + (size_t)HID * NCORR;                // 32 MB
        float*          corr = (float*)(Bpl + (size_t)HID * NCORR);     // 16 MB

        // W1-pack lives INSIDE corr (consumed by k_hidden2 before k_gemm6
        // writes corr).
        unsigned short* W1ph = (unsigned short*)corr;                    // 4 MB
        unsigned short* W1pl = W1ph + (size_t)K1 * HID;                  // 4 MB

        k_splitW<<<dim3(HID / 32, K1 / 64), 256, 0, stream>>>(W1, W1ph, W1pl, 16);
        k_splitW<<<dim3(NCORR / 32, HID / 64), 256, 0, stream>>>(W2, Bph, Bpl, 128);

        k_hidden2<<<dim3(HID / 128, B_SZ / 64), 256, 0, stream>>>(x, W1ph, W1pl, b1, h_hi, h_lo);

        dim3 g2(NCORR / 128, B_SZ / 64);    // 32 x 16 = 512 blocks
        k_gemm6<<<g2, 256, 0, stream>>>(h_hi, h_lo, Bph, Bpl, b2, corr);
        k_det<<<B_SZ, 128, 0, stream>>>(x, orbitals, corr, out, imag_off);
    } else {
        float* h    = (float*)d_ws;
        float* corr = h + (size_t)B_SZ * HID;
        k_hidden_f32<<<B_SZ, 256, 0, stream>>>(x, W1, b1, h);
        dim3 g2(NCORR / BN, B_SZ / BM);
        k_gemm<<<g2, 256, 0, stream>>>(h, W2, b2, corr);
        k_det<<<B_SZ, 128, 0, stream>>>(x, orbitals, corr, out, imag_off);
    }
}